// Round 1
// baseline (1149.374 us; speedup 1.0000x reference)
//
#include <hip/hip_runtime.h>
#include <math.h>

#define N_PTS 12000
#define KNN 16
#define TJ 256     // candidate tile size (LDS)
#define Q 2        // queries per wave
#define WPB 4      // waves per block

// ---------------------------------------------------------------------------
// Kernel 1: encoders. feats = tanh(x@Wf + bf) [N,64]; coords = tanh(x@Wl + bl)
// [N,16]; sq[i] = sum(coords[i]^2). One wave per row.
// ---------------------------------------------------------------------------
__global__ __launch_bounds__(256) void encoder_kernel(
    const float* __restrict__ x, const float* __restrict__ Wf, const float* __restrict__ bf,
    const float* __restrict__ Wl, const float* __restrict__ bl,
    float* __restrict__ feats, float* __restrict__ coords, float* __restrict__ sq)
{
  const int wave = threadIdx.x >> 6;
  const int lane = threadIdx.x & 63;
  const int i = blockIdx.x * 4 + wave;
  if (i >= N_PTS) return;
  float xv = x[i * 64 + lane];
  float accf = bf[lane];
  float accc = bl[lane & 15];
  #pragma unroll
  for (int k = 0; k < 64; ++k) {
    float xk = __shfl(xv, k);
    accf = fmaf(xk, Wf[k * 64 + lane], accf);
    accc = fmaf(xk, Wl[k * 16 + (lane & 15)], accc);
  }
  feats[i * 64 + lane] = tanhf(accf);
  float c = tanhf(accc);
  float cc = (lane < 16) ? c * c : 0.0f;
  cc += __shfl_xor(cc, 1);
  cc += __shfl_xor(cc, 2);
  cc += __shfl_xor(cc, 4);
  cc += __shfl_xor(cc, 8);
  if (lane < 16) coords[i * 16 + lane] = c;
  if (lane == 0) sq[i] = cc;
}

// ---------------------------------------------------------------------------
// Kernel 2: brute-force KNN (K=16, self excluded) + gaussian-weighted
// aggregation. Wave handles Q=2 queries; candidates staged transposed in LDS.
// Per-lane top-16 (replace-max) pruned by wave-shared threshold
// T = wave_min(per-lane 16th best)  -- valid global upper bound on the final
// 16th-smallest distance, so pruned candidates can never be in the answer.
// ---------------------------------------------------------------------------
__global__ __launch_bounds__(256) void knn_agg_kernel(
    const float* __restrict__ coords, const float* __restrict__ sq,
    const float* __restrict__ feats, float* __restrict__ agg)
{
  __shared__ float cT[16 * (TJ + 1)];  // transposed, padded: stride 257 -> 2-way max on write, free
  __shared__ float sqs[TJ];
  const int lane = threadIdx.x & 63;
  const int wave = threadIdx.x >> 6;
  const int qbase = blockIdx.x * (WPB * Q) + wave * Q;

  float ci[Q][16], sqi[Q];
  #pragma unroll
  for (int q = 0; q < Q; ++q) {
    #pragma unroll
    for (int d = 0; d < 16; ++d) ci[q][d] = coords[(qbase + q) * 16 + d];
    sqi[q] = sq[qbase + q];
  }

  float d16[Q][KNN]; int i16[Q][KNN];
  float wmax[Q], Tq[Q];
  #pragma unroll
  for (int q = 0; q < Q; ++q) {
    #pragma unroll
    for (int t = 0; t < KNN; ++t) { d16[q][t] = INFINITY; i16[q][t] = 0; }
    wmax[q] = INFINITY; Tq[q] = INFINITY;
  }

  const int numTiles = (N_PTS + TJ - 1) / TJ;  // 47
  for (int tile = 0; tile < numTiles; ++tile) {
    const int j0 = tile * TJ;
    __syncthreads();
    {
      const int d = threadIdx.x & 15;
      const int jl0 = threadIdx.x >> 4;  // 0..15
      #pragma unroll
      for (int p = 0; p < TJ / 16; ++p) {
        const int jl = jl0 + p * 16;
        const int j = j0 + jl;
        cT[d * (TJ + 1) + jl] = (j < N_PTS) ? coords[j * 16 + d] : 0.0f;
      }
      if (threadIdx.x < TJ)
        sqs[threadIdx.x] = (j0 + (int)threadIdx.x < N_PTS) ? sq[j0 + threadIdx.x] : INFINITY;
    }
    __syncthreads();

    #pragma unroll
    for (int h = 0; h < TJ / 64; ++h) {
      const int jl = h * 64 + lane;
      const int j = j0 + jl;
      const float sqj = sqs[jl];
      float cj[16];
      #pragma unroll
      for (int d = 0; d < 16; ++d) cj[d] = cT[d * (TJ + 1) + jl];  // stride-1 across lanes: conflict-free

      #pragma unroll
      for (int q = 0; q < Q; ++q) {
        float dot = 0.0f;
        #pragma unroll
        for (int d = 0; d < 16; ++d) dot = fmaf(ci[q][d], cj[d], dot);
        float d2 = fmaxf(fmaf(-2.0f, dot, sqi[q] + sqj), 0.0f);
        if (j == qbase + q || j >= N_PTS) d2 = INFINITY;

        const bool ins = d2 < Tq[q];   // Tq <= own wmax always
        if (__any(ins)) {              // wave-uniform branch
          if (ins) {
            const float om = wmax[q];
            bool done = false;
            #pragma unroll
            for (int t = 0; t < KNN; ++t) {  // replace current max slot
              const bool hit = (!done) && (d16[q][t] == om);
              if (hit) { d16[q][t] = d2; i16[q][t] = j; }
              done = done || hit;
            }
            float nm = d16[q][0];
            #pragma unroll
            for (int t = 1; t < KNN; ++t) nm = fmaxf(nm, d16[q][t]);
            wmax[q] = nm;
          }
          float tv = wmax[q];  // all lanes participate in the reduce
          #pragma unroll
          for (int off = 32; off >= 1; off >>= 1)
            tv = fminf(tv, __shfl_xor(tv, off));
          Tq[q] = tv;
        }
      }
    }
  }

  // ---- merge 64 lanes x 16 locals -> global top-16, aggregate on the fly ----
  #pragma unroll
  for (int q = 0; q < Q; ++q) {
    float lmin = d16[q][0]; int lidx = i16[q][0]; int lpos = 0;
    #pragma unroll
    for (int t = 1; t < KNN; ++t) {
      const bool b = d16[q][t] < lmin;
      lmin = b ? d16[q][t] : lmin; lidx = b ? i16[q][t] : lidx; lpos = b ? t : lpos;
    }
    float aggv = 0.0f;
    for (int r = 0; r < KNN; ++r) {
      float m = lmin; int mj = lidx; int msrc = lane;
      #pragma unroll
      for (int off = 32; off >= 1; off >>= 1) {  // argmin butterfly, tie-break by lane
        const float om = __shfl_xor(m, off);
        const int oj = __shfl_xor(mj, off);
        const int os = __shfl_xor(msrc, off);
        const bool take = (om < m) || (om == m && os < msrc);
        m = take ? om : m; mj = take ? oj : mj; msrc = take ? os : msrc;
      }
      if (lane == msrc) {  // winner removes its entry and recomputes local min
        #pragma unroll
        for (int t = 0; t < KNN; ++t) if (t == lpos) d16[q][t] = INFINITY;
        lmin = d16[q][0]; lidx = i16[q][0]; lpos = 0;
        #pragma unroll
        for (int t = 1; t < KNN; ++t) {
          const bool b = d16[q][t] < lmin;
          lmin = b ? d16[q][t] : lmin; lidx = b ? i16[q][t] : lidx; lpos = b ? t : lpos;
        }
      }
      const bool ok = (m < 1e37f);
      const float w = ok ? expf(-m) : 0.0f;
      const int jj = ok ? mj : 0;
      aggv = fmaf(w, feats[jj * 64 + lane], aggv);
    }
    agg[(qbase + q) * 64 + lane] = aggv;
  }
}

// ---------------------------------------------------------------------------
// Kernel 3: out = concat(feats, agg) @ W_out + b_out.  Wave per row.
// ---------------------------------------------------------------------------
__global__ __launch_bounds__(256) void out_kernel(
    const float* __restrict__ feats, const float* __restrict__ agg,
    const float* __restrict__ Wo, const float* __restrict__ bo,
    float* __restrict__ out)
{
  const int idx = blockIdx.x * 256 + threadIdx.x;
  const int i = idx >> 6, o = idx & 63;
  if (i >= N_PTS) return;
  float acc = bo[o];
  #pragma unroll
  for (int f = 0; f < 64; ++f)
    acc = fmaf(feats[i * 64 + f], Wo[f * 64 + o], acc);
  #pragma unroll
  for (int f = 0; f < 64; ++f)
    acc = fmaf(agg[i * 64 + f], Wo[(64 + f) * 64 + o], acc);
  out[i * 64 + o] = acc;
}

extern "C" void kernel_launch(void* const* d_in, const int* in_sizes, int n_in,
                              void* d_out, int out_size, void* d_ws, size_t ws_size,
                              hipStream_t stream) {
  const float* x  = (const float*)d_in[0];
  const float* Wf = (const float*)d_in[1];
  const float* bf = (const float*)d_in[2];
  const float* Wl = (const float*)d_in[3];
  const float* bl = (const float*)d_in[4];
  const float* Wo = (const float*)d_in[5];
  const float* bo = (const float*)d_in[6];
  float* out = (float*)d_out;

  char* ws = (char*)d_ws;
  float* feats  = (float*)(ws);                                // 12000*64*4 = 3,072,000 B
  float* coords = (float*)(ws + 3072000);                      // 12000*16*4 =   768,000 B
  float* sqv    = (float*)(ws + 3072000 + 768000);             // 12000*4    =    48,000 B
  float* agg    = (float*)(ws + 3072000 + 768000 + 48000);     // 12000*64*4 = 3,072,000 B

  encoder_kernel<<<3000, 256, 0, stream>>>(x, Wf, bf, Wl, bl, feats, coords, sqv);
  knn_agg_kernel<<<N_PTS / (WPB * Q), 256, 0, stream>>>(coords, sqv, feats, agg);
  out_kernel<<<3000, 256, 0, stream>>>(feats, agg, Wo, bo, out);
}

// Round 3
// 669.620 us; speedup vs baseline: 1.7165x; 1.7165x over previous
//
#include <hip/hip_runtime.h>
#include <math.h>

typedef unsigned long long u64;

#define N_PTS 12000
#define KNN 16
#define TJ 256     // candidate tile size (LDS)
#define Q 2        // queries per wave
#define WPB 4      // waves per block
#define NTILES ((N_PTS + TJ - 1) / TJ)   // 47
#define CSTRIDE (TJ + 2)  // pad +2: bank=(2d+jl)&31 -> max 2-way (free) on reads AND writes

// ---------------------------------------------------------------------------
// Kernel 1: encoders. feats = tanh(x@Wf + bf) [N,64]; coords = tanh(x@Wl + bl)
// [N,16]; sq[i] = sum(coords[i]^2). One wave per row.
// ---------------------------------------------------------------------------
__global__ __launch_bounds__(256) void encoder_kernel(
    const float* __restrict__ x, const float* __restrict__ Wf, const float* __restrict__ bf,
    const float* __restrict__ Wl, const float* __restrict__ bl,
    float* __restrict__ feats, float* __restrict__ coords, float* __restrict__ sq)
{
  const int wave = threadIdx.x >> 6;
  const int lane = threadIdx.x & 63;
  const int i = blockIdx.x * 4 + wave;
  if (i >= N_PTS) return;
  float xv = x[i * 64 + lane];
  float accf = bf[lane];
  float accc = bl[lane & 15];
  #pragma unroll
  for (int k = 0; k < 64; ++k) {
    float xk = __shfl(xv, k);
    accf = fmaf(xk, Wf[k * 64 + lane], accf);
    accc = fmaf(xk, Wl[k * 16 + (lane & 15)], accc);
  }
  feats[i * 64 + lane] = tanhf(accf);
  float c = tanhf(accc);
  float cc = (lane < 16) ? c * c : 0.0f;
  cc += __shfl_xor(cc, 1);
  cc += __shfl_xor(cc, 2);
  cc += __shfl_xor(cc, 4);
  cc += __shfl_xor(cc, 8);
  if (lane < 16) coords[i * 16 + lane] = c;
  if (lane == 0) sq[i] = cc;
}

// ---------------------------------------------------------------------------
// Branchless replace-max insert into an 8-slot u64 key table.
// Keys are (f32bits(d2)<<32)|j: globally UNIQUE -> equality match hits exactly
// one slot. Non-qualifying insert matches the impossible key ~0ull (slots hold
// sentinels 0x7F00000t<<32 or real keys with hi<=~0x42800000).
// ---------------------------------------------------------------------------
__device__ __forceinline__ void ins8(u64 key, u64* k8, u64& kmax) {
  const u64 om = (key < kmax) ? kmax : ~0ull;
  #pragma unroll
  for (int t = 0; t < 8; ++t)
    k8[t] = (k8[t] == om) ? key : k8[t];
  u64 a = k8[0] > k8[1] ? k8[0] : k8[1];
  u64 b = k8[2] > k8[3] ? k8[2] : k8[3];
  u64 c = k8[4] > k8[5] ? k8[4] : k8[5];
  u64 d = k8[6] > k8[7] ? k8[6] : k8[7];
  a = a > b ? a : b;
  c = c > d ? c : d;
  kmax = a > c ? a : c;
}

__device__ __forceinline__ u64 shflx_u64(u64 v, int off) {
  int lo = __shfl_xor((int)(unsigned)v, off);
  int hi = __shfl_xor((int)(unsigned)(v >> 32), off);
  return ((u64)(unsigned)hi << 32) | (unsigned)lo;
}

__device__ __forceinline__ u64 minbfly(u64 m) {
  #pragma unroll
  for (int off = 32; off >= 1; off >>= 1) {
    u64 o = shflx_u64(m, off);
    m = (o < m) ? o : m;
  }
  return m;
}

// ---------------------------------------------------------------------------
// Kernel 2: brute-force KNN (K=16, self excluded) + gaussian aggregation.
// Wave = 2 queries. Each lane keeps TWO top-8 u64 half-tables (h<2 / h>=2),
// branchless always-insert. Exactness: if a true top-16 member was evicted
// from a half-table, that table's final max < T16 -> per-query flag -> exact
// fallback kernel (statistically never fires: needs >=9 of the top-16 on one
// of 128 half-lanes).
// ---------------------------------------------------------------------------
__global__ __launch_bounds__(256) void knn_agg_kernel(
    const float* __restrict__ coords, const float* __restrict__ sq,
    const float* __restrict__ feats, float* __restrict__ agg,
    int* __restrict__ flags)
{
  __shared__ float cT[16 * CSTRIDE];
  __shared__ float sqs[TJ];
  const int lane = threadIdx.x & 63;
  const int wave = threadIdx.x >> 6;
  const int qbase = blockIdx.x * (WPB * Q) + wave * Q;

  float ci[Q][16], sqi[Q];
  #pragma unroll
  for (int q = 0; q < Q; ++q) {
    #pragma unroll
    for (int d = 0; d < 16; ++d) ci[q][d] = coords[(qbase + q) * 16 + d];
    sqi[q] = sq[qbase + q];
  }

  u64 k8a[Q][8], k8b[Q][8], kmaxA[Q], kmaxB[Q];
  #pragma unroll
  for (int q = 0; q < Q; ++q) {
    #pragma unroll
    for (int t = 0; t < 8; ++t) {
      k8a[q][t] = ((u64)(0x7F000000u + t) << 32);   // distinct sentinels
      k8b[q][t] = ((u64)(0x7F000000u + t) << 32);
    }
    kmaxA[q] = ((u64)0x7F000007u << 32);
    kmaxB[q] = ((u64)0x7F000007u << 32);
  }

  for (int tile = 0; tile < NTILES; ++tile) {
    const int j0 = tile * TJ;
    __syncthreads();
    {
      const int d = threadIdx.x & 15;
      const int jl0 = threadIdx.x >> 4;  // 0..15
      #pragma unroll
      for (int p = 0; p < TJ / 16; ++p) {
        const int jl = jl0 + p * 16;
        const int j = j0 + jl;
        cT[d * CSTRIDE + jl] = (j < N_PTS) ? coords[j * 16 + d] : 0.0f;
      }
      if (threadIdx.x < TJ)
        sqs[threadIdx.x] = (j0 + (int)threadIdx.x < N_PTS) ? sq[j0 + threadIdx.x] : 0.0f;
    }
    __syncthreads();

    #pragma unroll
    for (int h = 0; h < 4; ++h) {
      const int jl = h * 64 + lane;
      const int j = j0 + jl;
      const float sqj = sqs[jl];
      float dot0 = 0.0f, dot1 = 0.0f;
      #pragma unroll
      for (int d = 0; d < 16; ++d) {
        const float cv = cT[d * CSTRIDE + jl];  // lanes stride-1: conflict-free
        dot0 = fmaf(ci[0][d], cv, dot0);
        dot1 = fmaf(ci[1][d], cv, dot1);
      }
      float d20 = fmaxf(fmaf(-2.0f, dot0, sqi[0] + sqj), 0.0f);
      float d21 = fmaxf(fmaf(-2.0f, dot1, sqi[1] + sqj), 0.0f);
      unsigned hi0 = (j == qbase + 0 || j >= N_PTS) ? 0xFFFFFFFFu : __float_as_uint(d20);
      unsigned hi1 = (j == qbase + 1 || j >= N_PTS) ? 0xFFFFFFFFu : __float_as_uint(d21);
      const u64 key0 = ((u64)hi0 << 32) | (unsigned)j;
      const u64 key1 = ((u64)hi1 << 32) | (unsigned)j;
      if (h < 2) {
        ins8(key0, k8a[0], kmaxA[0]);
        ins8(key1, k8a[1], kmaxA[1]);
      } else {
        ins8(key0, k8b[0], kmaxB[0]);
        ins8(key1, k8b[1], kmaxB[1]);
      }
    }
  }

  // ---- merge 64 lanes x 16 locals -> global top-16, aggregate on the fly ----
  #pragma unroll
  for (int q = 0; q < Q; ++q) {
    u64 tab[16];
    #pragma unroll
    for (int t = 0; t < 8; ++t) { tab[t] = k8a[q][t]; tab[8 + t] = k8b[q][t]; }
    u64 lmin = tab[0];
    #pragma unroll
    for (int t = 1; t < 16; ++t) lmin = (tab[t] < lmin) ? tab[t] : lmin;

    float aggv = 0.0f;
    u64 T16 = 0;
    for (int r = 0; r < KNN; ++r) {
      const u64 m = minbfly(lmin);         // global min; identical on all lanes
      if (lmin == m) {                     // unique winner lane removes entry
        #pragma unroll
        for (int t = 0; t < 16; ++t) tab[t] = (tab[t] == m) ? ~0ull : tab[t];
        lmin = tab[0];
        #pragma unroll
        for (int t = 1; t < 16; ++t) lmin = (tab[t] < lmin) ? tab[t] : lmin;
      }
      const unsigned hi = (unsigned)(m >> 32);
      const bool ok = hi < 0x7F000000u;
      const float w = ok ? expf(-__uint_as_float(hi)) : 0.0f;
      const int jj = ok ? (int)(unsigned)(m & 0xFFFFFFFFull) : 0;
      aggv = fmaf(w, feats[jj * 64 + lane], aggv);
      T16 = m;
    }
    agg[(qbase + q) * 64 + lane] = aggv;
    const int fl = __any((kmaxA[q] < T16) || (kmaxB[q] < T16));
    if (lane == 0) flags[qbase + q] = fl;
  }
}

// ---------------------------------------------------------------------------
// Kernel 2b: exact fallback for flagged queries (expected: zero). One wave per
// query; 16 passes of strictly-ascending global argmin over unique u64 keys.
// ---------------------------------------------------------------------------
__global__ __launch_bounds__(256) void knn_fixup_kernel(
    const float* __restrict__ coords, const float* __restrict__ sq,
    const float* __restrict__ feats, const int* __restrict__ flags,
    float* __restrict__ agg)
{
  const int wave = threadIdx.x >> 6;
  const int lane = threadIdx.x & 63;
  const int i = blockIdx.x * 4 + wave;
  if (i >= N_PTS) return;
  if (!flags[i]) return;
  float ci[16];
  #pragma unroll
  for (int d = 0; d < 16; ++d) ci[d] = coords[i * 16 + d];
  const float sqi = sq[i];
  float aggv = 0.0f;
  u64 prev = 0;
  for (int r = 0; r < KNN; ++r) {
    u64 best = ~0ull;
    for (int j = lane; j < N_PTS; j += 64) {
      float dot = 0.0f;
      #pragma unroll
      for (int d = 0; d < 16; ++d) dot = fmaf(ci[d], coords[j * 16 + d], dot);
      const float d2 = fmaxf(fmaf(-2.0f, dot, sqi + sq[j]), 0.0f);
      const unsigned hi = (j == i) ? 0xFFFFFFFFu : __float_as_uint(d2);
      const u64 key = ((u64)hi << 32) | (unsigned)j;
      const bool cand = (r == 0) || (key > prev);
      if (cand && key < best) best = key;
    }
    const u64 m = minbfly(best);
    prev = m;
    const unsigned hi = (unsigned)(m >> 32);
    const bool ok = hi < 0x7F000000u;
    const float w = ok ? expf(-__uint_as_float(hi)) : 0.0f;
    const int jj = ok ? (int)(unsigned)(m & 0xFFFFFFFFull) : 0;
    aggv = fmaf(w, feats[jj * 64 + lane], aggv);
  }
  agg[i * 64 + lane] = aggv;
}

// ---------------------------------------------------------------------------
// Kernel 3: out = concat(feats, agg) @ W_out + b_out.  Wave per row.
// ---------------------------------------------------------------------------
__global__ __launch_bounds__(256) void out_kernel(
    const float* __restrict__ feats, const float* __restrict__ agg,
    const float* __restrict__ Wo, const float* __restrict__ bo,
    float* __restrict__ out)
{
  const int idx = blockIdx.x * 256 + threadIdx.x;
  const int i = idx >> 6, o = idx & 63;
  if (i >= N_PTS) return;
  float acc = bo[o];
  #pragma unroll
  for (int f = 0; f < 64; ++f)
    acc = fmaf(feats[i * 64 + f], Wo[f * 64 + o], acc);
  #pragma unroll
  for (int f = 0; f < 64; ++f)
    acc = fmaf(agg[i * 64 + f], Wo[(64 + f) * 64 + o], acc);
  out[i * 64 + o] = acc;
}

extern "C" void kernel_launch(void* const* d_in, const int* in_sizes, int n_in,
                              void* d_out, int out_size, void* d_ws, size_t ws_size,
                              hipStream_t stream) {
  const float* x  = (const float*)d_in[0];
  const float* Wf = (const float*)d_in[1];
  const float* bf = (const float*)d_in[2];
  const float* Wl = (const float*)d_in[3];
  const float* bl = (const float*)d_in[4];
  const float* Wo = (const float*)d_in[5];
  const float* bo = (const float*)d_in[6];
  float* out = (float*)d_out;

  char* ws = (char*)d_ws;
  float* feats  = (float*)(ws);                    // 3,072,000 B
  float* coords = (float*)(ws + 3072000);          //   768,000 B
  float* sqv    = (float*)(ws + 3840000);          //    48,000 B
  float* agg    = (float*)(ws + 3888000);          // 3,072,000 B
  int*   flags  = (int*)  (ws + 6960000);          //    48,000 B

  encoder_kernel<<<3000, 256, 0, stream>>>(x, Wf, bf, Wl, bl, feats, coords, sqv);
  knn_agg_kernel<<<N_PTS / (WPB * Q), 256, 0, stream>>>(coords, sqv, feats, agg, flags);
  knn_fixup_kernel<<<3000, 256, 0, stream>>>(coords, sqv, feats, flags, agg);
  out_kernel<<<3000, 256, 0, stream>>>(feats, agg, Wo, bo, out);
}

// Round 4
// 525.030 us; speedup vs baseline: 2.1892x; 1.2754x over previous
//
#include <hip/hip_runtime.h>
#include <math.h>

typedef unsigned long long u64;

#define N_PTS 12000
#define KNN 16
#define TJ 256     // candidate tile size (LDS)
#define Q 2        // queries per wave
#define WPB 4      // waves per block
#define NTILES ((N_PTS + TJ - 1) / TJ)   // 47
#define WARM 2     // warmup tiles: insert all 4 candidates
#define CSTRIDE (TJ + 2)  // bank=(2d+jl)&31 -> max 2-way (free)

// ---------------------------------------------------------------------------
// Kernel 1: encoders. feats = tanh(x@Wf + bf); coords = tanh(x@Wl + bl);
// sq[i] = sum(coords[i]^2). One wave per row.
// ---------------------------------------------------------------------------
__global__ __launch_bounds__(256) void encoder_kernel(
    const float* __restrict__ x, const float* __restrict__ Wf, const float* __restrict__ bf,
    const float* __restrict__ Wl, const float* __restrict__ bl,
    float* __restrict__ feats, float* __restrict__ coords, float* __restrict__ sq)
{
  const int wave = threadIdx.x >> 6;
  const int lane = threadIdx.x & 63;
  const int i = blockIdx.x * 4 + wave;
  if (i >= N_PTS) return;
  float xv = x[i * 64 + lane];
  float accf = bf[lane];
  float accc = bl[lane & 15];
  #pragma unroll
  for (int k = 0; k < 64; ++k) {
    float xk = __shfl(xv, k);
    accf = fmaf(xk, Wf[k * 64 + lane], accf);
    accc = fmaf(xk, Wl[k * 16 + (lane & 15)], accc);
  }
  feats[i * 64 + lane] = tanhf(accf);
  float c = tanhf(accc);
  float cc = (lane < 16) ? c * c : 0.0f;
  cc += __shfl_xor(cc, 1);
  cc += __shfl_xor(cc, 2);
  cc += __shfl_xor(cc, 4);
  cc += __shfl_xor(cc, 8);
  if (lane < 16) coords[i * 16 + lane] = c;
  if (lane == 0) sq[i] = cc;
}

// ---------------------------------------------------------------------------
// Branchless replace-max insert into an 8-slot u64 key table.
// Keys (f32bits(d2)<<32)|j are globally unique and each key is offered at
// most once, so equality-match hits exactly one slot.
// ---------------------------------------------------------------------------
__device__ __forceinline__ void ins8(u64 key, u64* k8, u64& kmax) {
  const u64 om = (key < kmax) ? kmax : ~0ull;
  #pragma unroll
  for (int t = 0; t < 8; ++t)
    k8[t] = (k8[t] == om) ? key : k8[t];
  u64 a = k8[0] > k8[1] ? k8[0] : k8[1];
  u64 b = k8[2] > k8[3] ? k8[2] : k8[3];
  u64 c = k8[4] > k8[5] ? k8[4] : k8[5];
  u64 d = k8[6] > k8[7] ? k8[6] : k8[7];
  a = a > b ? a : b;
  c = c > d ? c : d;
  kmax = a > c ? a : c;
}

__device__ __forceinline__ u64 shflx_u64(u64 v, int off) {
  int lo = __shfl_xor((int)(unsigned)v, off);
  int hi = __shfl_xor((int)(unsigned)(v >> 32), off);
  return ((u64)(unsigned)hi << 32) | (unsigned)lo;
}

__device__ __forceinline__ u64 minbfly(u64 m) {
  #pragma unroll
  for (int off = 32; off >= 1; off >>= 1) {
    u64 o = shflx_u64(m, off);
    m = (o < m) ? o : m;
  }
  return m;
}

// ---------------------------------------------------------------------------
// Kernel 2: brute-force KNN (K=16, self excluded) + gaussian aggregation.
// Wave = 2 queries, one 8-slot u64 table per lane per query. Per tile each
// lane inserts only its quad-min; candidates with d2 > T (T = 2nd-smallest
// lane 8th-best, a sound upper bound on the global 16th-best) are provably
// outside the top-16 and may be skipped; the rare "2nd of quad <= T" case is
// handled by a __any-gated full insert. Evictions (>8 of top-16 on one lane)
// are caught by the kmax<T16 flag -> exact fallback kernel.
// ---------------------------------------------------------------------------
__global__ __launch_bounds__(256) void knn_agg_kernel(
    const float* __restrict__ coords, const float* __restrict__ sq,
    const float* __restrict__ feats, float* __restrict__ agg,
    int* __restrict__ flags)
{
  __shared__ float cT[16 * CSTRIDE];
  __shared__ float sqs[TJ];
  const int lane = threadIdx.x & 63;
  const int wave = threadIdx.x >> 6;
  const int qbase = blockIdx.x * (WPB * Q) + wave * Q;

  float ci[Q][16], sqi[Q];
  #pragma unroll
  for (int q = 0; q < Q; ++q) {
    #pragma unroll
    for (int d = 0; d < 16; ++d) ci[q][d] = coords[(qbase + q) * 16 + d];
    sqi[q] = sq[qbase + q];
  }

  u64 k8[Q][8], kmax[Q];
  float T[Q];
  #pragma unroll
  for (int q = 0; q < Q; ++q) {
    #pragma unroll
    for (int t = 0; t < 8; ++t)
      k8[q][t] = ((u64)(0x7F000000u + t) << 32);   // distinct sentinels
    kmax[q] = ((u64)0x7F000007u << 32);
    T[q] = INFINITY;
  }

  // staging thread mapping: jl = tid>>2 (+64p), g = tid&3 -> float4
  const int s_jl = threadIdx.x >> 2;
  const int s_g  = threadIdx.x & 3;

  for (int tile = 0; tile < NTILES; ++tile) {
    const int j0 = tile * TJ;
    __syncthreads();
    #pragma unroll
    for (int p = 0; p < 4; ++p) {
      const int jl = s_jl + p * 64;
      const int j = j0 + jl;
      float4 v = make_float4(0.f, 0.f, 0.f, 0.f);
      if (j < N_PTS) v = ((const float4*)(coords + j * 16))[s_g];
      cT[(s_g * 4 + 0) * CSTRIDE + jl] = v.x;
      cT[(s_g * 4 + 1) * CSTRIDE + jl] = v.y;
      cT[(s_g * 4 + 2) * CSTRIDE + jl] = v.z;
      cT[(s_g * 4 + 3) * CSTRIDE + jl] = v.w;
    }
    if (threadIdx.x < TJ)
      sqs[threadIdx.x] = (j0 + (int)threadIdx.x < N_PTS) ? sq[j0 + threadIdx.x] : 0.0f;
    __syncthreads();

    float dq[Q][4];
    #pragma unroll
    for (int h = 0; h < 4; ++h) {
      const int jl = h * 64 + lane;
      const int j = j0 + jl;
      const float sqj = sqs[jl];
      float dot0 = 0.0f, dot1 = 0.0f;
      #pragma unroll
      for (int d = 0; d < 16; ++d) {
        const float cv = cT[d * CSTRIDE + jl];  // lanes stride-1: conflict-free
        dot0 = fmaf(ci[0][d], cv, dot0);
        dot1 = fmaf(ci[1][d], cv, dot1);
      }
      float d20 = fmaxf(fmaf(-2.0f, dot0, sqi[0] + sqj), 0.0f);
      float d21 = fmaxf(fmaf(-2.0f, dot1, sqi[1] + sqj), 0.0f);
      if (j == qbase + 0 || j >= N_PTS) d20 = INFINITY;  // key hi=0x7F800000 < sentinels? no: > real, never inserted
      if (j == qbase + 1 || j >= N_PTS) d21 = INFINITY;
      dq[0][h] = d20;
      dq[1][h] = d21;
    }

    if (tile < WARM) {
      #pragma unroll
      for (int q = 0; q < Q; ++q)
        #pragma unroll
        for (int h = 0; h < 4; ++h) {
          const u64 key = ((u64)__float_as_uint(dq[q][h]) << 32) | (unsigned)(j0 + h * 64 + lane);
          ins8(key, k8[q], kmax[q]);
        }
    } else {
      #pragma unroll
      for (int q = 0; q < Q; ++q) {
        const float a = dq[q][0], b = dq[q][1], c = dq[q][2], d = dq[q][3];
        const float lo1 = fminf(a, b), hi1 = fmaxf(a, b);
        const float lo2 = fminf(c, d), hi2 = fmaxf(c, d);
        const int h1 = (a <= b) ? 0 : 1;
        const int h2 = (c <= d) ? 2 : 3;
        const float dm = fminf(lo1, lo2);
        const int hm = (lo1 <= lo2) ? h1 : h2;
        const float s2 = fminf(fmaxf(lo1, lo2), fminf(hi1, hi2));
        const u64 key = ((u64)__float_as_uint(dm) << 32) | (unsigned)(j0 + hm * 64 + lane);
        ins8(key, k8[q], kmax[q]);
        if (__any(s2 <= T[q])) {   // rare: 2nd-of-quad might be in top-16
          #pragma unroll
          for (int h = 0; h < 4; ++h) {
            const unsigned hi = (h == hm) ? 0xFFFFFFFFu : __float_as_uint(dq[q][h]);
            const u64 k2 = ((u64)hi << 32) | (unsigned)(j0 + h * 64 + lane);
            ins8(k2, k8[q], kmax[q]);
          }
        }
      }
    }

    if (tile & 1) {  // refresh T: 2nd-smallest lane kmax-d2 (sound bound, monotone)
      #pragma unroll
      for (int q = 0; q < Q; ++q) {
        float m1 = __uint_as_float((unsigned)(kmax[q] >> 32));
        float m2 = INFINITY;
        #pragma unroll
        for (int off = 32; off >= 1; off >>= 1) {
          const float o1 = __shfl_xor(m1, off);
          const float o2 = __shfl_xor(m2, off);
          const float lo = fminf(m1, o1);
          const float hi = fmaxf(m1, o1);
          m2 = fminf(fminf(m2, o2), hi);
          m1 = lo;
        }
        T[q] = m2;
      }
    }
  }

  // ---- merge 64 lanes x 8 locals -> global top-16, aggregate on the fly ----
  #pragma unroll
  for (int q = 0; q < Q; ++q) {
    u64 lmin = k8[q][0];
    #pragma unroll
    for (int t = 1; t < 8; ++t) lmin = (k8[q][t] < lmin) ? k8[q][t] : lmin;

    float aggv = 0.0f;
    u64 T16 = 0;
    for (int r = 0; r < KNN; ++r) {
      const u64 m = minbfly(lmin);         // unique global min
      if (lmin == m) {                     // winner removes its entry
        #pragma unroll
        for (int t = 0; t < 8; ++t) k8[q][t] = (k8[q][t] == m) ? ~0ull : k8[q][t];
        lmin = k8[q][0];
        #pragma unroll
        for (int t = 1; t < 8; ++t) lmin = (k8[q][t] < lmin) ? k8[q][t] : lmin;
      }
      const unsigned hi = (unsigned)(m >> 32);
      const bool ok = hi < 0x7F000000u;
      const float w = ok ? expf(-__uint_as_float(hi)) : 0.0f;
      const int jj = ok ? (int)(unsigned)(m & 0xFFFFFFFFull) : 0;
      aggv = fmaf(w, feats[jj * 64 + lane], aggv);
      T16 = m;
    }
    agg[(qbase + q) * 64 + lane] = aggv;
    const int fl = __any(kmax[q] < T16);   // eviction of a top-16 member
    if (lane == 0) flags[qbase + q] = fl;
  }
}

// ---------------------------------------------------------------------------
// Kernel 2b: exact fallback for flagged queries (expected: zero).
// ---------------------------------------------------------------------------
__global__ __launch_bounds__(256) void knn_fixup_kernel(
    const float* __restrict__ coords, const float* __restrict__ sq,
    const float* __restrict__ feats, const int* __restrict__ flags,
    float* __restrict__ agg)
{
  const int wave = threadIdx.x >> 6;
  const int lane = threadIdx.x & 63;
  const int i = blockIdx.x * 4 + wave;
  if (i >= N_PTS) return;
  if (!flags[i]) return;
  float ci[16];
  #pragma unroll
  for (int d = 0; d < 16; ++d) ci[d] = coords[i * 16 + d];
  const float sqi = sq[i];
  float aggv = 0.0f;
  u64 prev = 0;
  for (int r = 0; r < KNN; ++r) {
    u64 best = ~0ull;
    for (int j = lane; j < N_PTS; j += 64) {
      float dot = 0.0f;
      #pragma unroll
      for (int d = 0; d < 16; ++d) dot = fmaf(ci[d], coords[j * 16 + d], dot);
      const float d2 = fmaxf(fmaf(-2.0f, dot, sqi + sq[j]), 0.0f);
      const unsigned hi = (j == i) ? 0xFFFFFFFFu : __float_as_uint(d2);
      const u64 key = ((u64)hi << 32) | (unsigned)j;
      const bool cand = (r == 0) || (key > prev);
      if (cand && key < best) best = key;
    }
    const u64 m = minbfly(best);
    prev = m;
    const unsigned hi = (unsigned)(m >> 32);
    const bool ok = hi < 0x7F000000u;
    const float w = ok ? expf(-__uint_as_float(hi)) : 0.0f;
    const int jj = ok ? (int)(unsigned)(m & 0xFFFFFFFFull) : 0;
    aggv = fmaf(w, feats[jj * 64 + lane], aggv);
  }
  agg[i * 64 + lane] = aggv;
}

// ---------------------------------------------------------------------------
// Kernel 3: out = concat(feats, agg) @ W_out + b_out.  Wave per row.
// ---------------------------------------------------------------------------
__global__ __launch_bounds__(256) void out_kernel(
    const float* __restrict__ feats, const float* __restrict__ agg,
    const float* __restrict__ Wo, const float* __restrict__ bo,
    float* __restrict__ out)
{
  const int idx = blockIdx.x * 256 + threadIdx.x;
  const int i = idx >> 6, o = idx & 63;
  if (i >= N_PTS) return;
  float acc = bo[o];
  #pragma unroll
  for (int f = 0; f < 64; ++f)
    acc = fmaf(feats[i * 64 + f], Wo[f * 64 + o], acc);
  #pragma unroll
  for (int f = 0; f < 64; ++f)
    acc = fmaf(agg[i * 64 + f], Wo[(64 + f) * 64 + o], acc);
  out[i * 64 + o] = acc;
}

extern "C" void kernel_launch(void* const* d_in, const int* in_sizes, int n_in,
                              void* d_out, int out_size, void* d_ws, size_t ws_size,
                              hipStream_t stream) {
  const float* x  = (const float*)d_in[0];
  const float* Wf = (const float*)d_in[1];
  const float* bf = (const float*)d_in[2];
  const float* Wl = (const float*)d_in[3];
  const float* bl = (const float*)d_in[4];
  const float* Wo = (const float*)d_in[5];
  const float* bo = (const float*)d_in[6];
  float* out = (float*)d_out;

  char* ws = (char*)d_ws;
  float* feats  = (float*)(ws);                    // 3,072,000 B
  float* coords = (float*)(ws + 3072000);          //   768,000 B
  float* sqv    = (float*)(ws + 3840000);          //    48,000 B
  float* agg    = (float*)(ws + 3888000);          // 3,072,000 B
  int*   flags  = (int*)  (ws + 6960000);          //    48,000 B

  encoder_kernel<<<3000, 256, 0, stream>>>(x, Wf, bf, Wl, bl, feats, coords, sqv);
  knn_agg_kernel<<<N_PTS / (WPB * Q), 256, 0, stream>>>(coords, sqv, feats, agg, flags);
  knn_fixup_kernel<<<3000, 256, 0, stream>>>(coords, sqv, feats, flags, agg);
  out_kernel<<<3000, 256, 0, stream>>>(feats, agg, Wo, bo, out);
}